// Round 5
// baseline (139.553 us; speedup 1.0000x reference)
//
#include <hip/hip_runtime.h>
#include <hip/hip_bf16.h>

// out[i] = x_i @ Q @ x_i, x [1024,2048] fp32 binary, Q [2048,2048] fp32.
// Identity: x^T Q x == x^T Q^T x -> MFMA B-operand (N x K) = row-major Q.
// Round 5: R2 shape (128x128 block, KSPLIT=8, 1024 blocks) + 32x32x16 frags
// (2x FLOP per LDS byte, acc only 64 regs/wave in 2x2 wave grid) + NEW
// epilogue: x-mask tile staged into LDS (reusing the 32KB staging buffer),
// killing the 64-128 per-lane global scalar loads that serialized R2-R4.

#define B_ROWS 1024
#define N_BITS 2048

#define BM 128
#define BN 128
#define BK 64
#define KSPLIT 8
#define KPER (N_BITS / KSPLIT)   // 256
#define KITERS (KPER / BK)       // 4

typedef __bf16 bf16_t;
typedef __bf16 bf16x8 __attribute__((ext_vector_type(8)));
typedef float f32x16 __attribute__((ext_vector_type(16)));

__device__ __forceinline__ void load16_to_lds(const void* g, void* l) {
  __builtin_amdgcn_global_load_lds(
      (__attribute__((address_space(1))) void*)(g),
      (__attribute__((address_space(3))) void*)(l),
      16, 0, 0);
}

// prep: fp32 -> bf16 for x (2M) and Q (4M) into ws; zero out[1024].
__global__ __launch_bounds__(256) void prep_kernel(
    const float* __restrict__ x, const float* __restrict__ Q,
    bf16_t* __restrict__ xb, bf16_t* __restrict__ qb, float* __restrict__ out) {
  const int tid = blockIdx.x * 256 + threadIdx.x;
  if (tid < B_ROWS) out[tid] = 0.0f;
  const int XTH = (B_ROWS * N_BITS) / 8;
  const float* src;
  bf16_t* dst;
  if (tid < XTH) {
    size_t o = (size_t)tid * 8;
    src = x + o;
    dst = xb + o;
  } else {
    size_t o = (size_t)(tid - XTH) * 8;
    src = Q + o;
    dst = qb + o;
  }
  float4 v0 = ((const float4*)src)[0];
  float4 v1 = ((const float4*)src)[1];
  union { int4 i4; __hip_bfloat16 h[8]; } u;
  u.h[0] = __float2bfloat16(v0.x);
  u.h[1] = __float2bfloat16(v0.y);
  u.h[2] = __float2bfloat16(v0.z);
  u.h[3] = __float2bfloat16(v0.w);
  u.h[4] = __float2bfloat16(v1.x);
  u.h[5] = __float2bfloat16(v1.y);
  u.h[6] = __float2bfloat16(v1.z);
  u.h[7] = __float2bfloat16(v1.w);
  ((int4*)dst)[0] = u.i4;
}

// GEMM S = Xb @ Qb^T (32x32x16 frags) + LDS-masked row-dot + atomicAdd.
// 4 waves in 2x2; each wave owns a 64x64 tile = 2x2 frags of 32x32.
__global__ __launch_bounds__(256) void qubo_kernel(
    const bf16_t* __restrict__ Xb, const bf16_t* __restrict__ Qb,
    float* __restrict__ out) {
  __shared__ bf16_t lds[(BM + BN) * BK];   // 32 KB; A at 0, B at BM*BK
  bf16_t* ldsA = lds;
  bf16_t* ldsB = lds + BM * BK;

  const int tid  = threadIdx.x;
  const int lane = tid & 63;
  const int wave = tid >> 6;
  const int wr   = wave >> 1;    // m-half (0..1)
  const int wc   = wave & 1;     // n-half (0..1)
  const int ln31 = lane & 31;
  const int l5   = lane >> 5;    // 0..1

  const int m0    = blockIdx.y * BM;
  const int n0    = blockIdx.x * BN;
  const int kbase = blockIdx.z * KPER;

  // Staging: 128 rows x 8 chunks (16B) per tile = 1024 chunks = 4 per thread.
  // LDS dest linear in tid (row*128B + slot*16B == pass*4096B + tid*16B, as
  // global_load_lds requires); GLOBAL chunk XOR-swizzled so LDS slot s of
  // row r holds global chunk s ^ (r&7) -> conflict-light frag ds_read_b128.
  const int srow = tid >> 3;              // 0..31 (row within 32-row pass)
  const int gch  = (tid & 7) ^ (srow & 7);  // swizzled global chunk

  f32x16 acc[2][2];
#pragma unroll
  for (int i = 0; i < 2; ++i)
#pragma unroll
    for (int j = 0; j < 2; ++j)
#pragma unroll
      for (int r = 0; r < 16; ++r) acc[i][j][r] = 0.f;

  for (int kt = 0; kt < KITERS; ++kt) {
    const int k0 = kbase + kt * BK;
#pragma unroll
    for (int p = 0; p < 4; ++p) {
      const int r = p * 32 + srow;
      load16_to_lds(Xb + (size_t)(m0 + r) * N_BITS + k0 + gch * 8,
                    ldsA + r * BK + (tid & 7) * 8);
      load16_to_lds(Qb + (size_t)(n0 + r) * N_BITS + k0 + gch * 8,
                    ldsB + r * BK + (tid & 7) * 8);
    }
    __syncthreads();

#pragma unroll
    for (int ks = 0; ks < 4; ++ks) {
      // frag row = base + ln31 (base % 32 == 0), wanted chunk = ks*2 + l5,
      // stored at slot (ks*2+l5) ^ (row&7) = ^ (ln31&7)
      const int ch = ((ks * 2 + l5) ^ (ln31 & 7)) * 8;
      bf16x8 a[2], b[2];
#pragma unroll
      for (int mi = 0; mi < 2; ++mi)
        a[mi] = *(const bf16x8*)&ldsA[(wr * 64 + mi * 32 + ln31) * BK + ch];
#pragma unroll
      for (int ni = 0; ni < 2; ++ni)
        b[ni] = *(const bf16x8*)&ldsB[(wc * 64 + ni * 32 + ln31) * BK + ch];
#pragma unroll
      for (int mi = 0; mi < 2; ++mi)
#pragma unroll
        for (int ni = 0; ni < 2; ++ni)
          acc[mi][ni] = __builtin_amdgcn_mfma_f32_32x32x16_bf16(
              a[mi], b[ni], acc[mi][ni], 0, 0, 0);
    }
    __syncthreads();
  }

  // Stage the x-mask tile X[m0:+128, n0:+128] (bf16, 32 KB) into the SAME lds
  // buffer: 128 rows x 16 chunks = 2048 chunks = 8 per thread; dest linear
  // (row*256B + slot*16B == pass*4096B + tid*16B). No swizzle needed: epilogue
  // reads are u16 with consecutive lanes on consecutive cols (2-way, free).
  bf16_t* maskL = lds;
#pragma unroll
  for (int p = 0; p < 8; ++p) {
    const int r = p * 16 + (tid >> 4);
    load16_to_lds(Xb + (size_t)(m0 + r) * N_BITS + n0 + (tid & 15) * 8,
                  maskL + r * BN + (tid & 15) * 8);
  }
  __syncthreads();

  // Epilogue. 32x32 C/D: col = lane&31, row = (r&3) + 8*(r>>2) + 4*(lane>>5).
  // Mask read from LDS (no global). Reduce 32 lanes (xor 1..16 keeps l5), one
  // atomic per row per block.
#pragma unroll
  for (int mi = 0; mi < 2; ++mi) {
#pragma unroll
    for (int r = 0; r < 16; ++r) {
      const int rloc = wr * 64 + mi * 32 + (r & 3) + 8 * (r >> 2) + 4 * l5;
      float s = 0.f;
#pragma unroll
      for (int ni = 0; ni < 2; ++ni) {
        const int cloc = wc * 64 + ni * 32 + ln31;
        s += acc[mi][ni][r] * (float)maskL[rloc * BN + cloc];
      }
      s += __shfl_xor(s, 1);
      s += __shfl_xor(s, 2);
      s += __shfl_xor(s, 4);
      s += __shfl_xor(s, 8);
      s += __shfl_xor(s, 16);
      if (ln31 == 0) atomicAdd(&out[m0 + rloc], s);
    }
  }
}

extern "C" void kernel_launch(void* const* d_in, const int* in_sizes, int n_in,
                              void* d_out, int out_size, void* d_ws, size_t ws_size,
                              hipStream_t stream) {
  const float* x = (const float*)d_in[0];
  const float* Q = (const float*)d_in[1];
  float* out = (float*)d_out;

  bf16_t* xb = (bf16_t*)d_ws;                                        // 4 MB
  bf16_t* qb = (bf16_t*)((char*)d_ws + (size_t)B_ROWS * N_BITS * 2); // 8 MB

  prep_kernel<<<3072, 256, 0, stream>>>(x, Q, xb, qb, out);

  dim3 grid(N_BITS / BN, B_ROWS / BM, KSPLIT);  // (16, 8, 8) = 1024 blocks
  qubo_kernel<<<grid, dim3(256), 0, stream>>>(xb, qb, out);
}

// Round 6
// 91.906 us; speedup vs baseline: 1.5184x; 1.5184x over previous
//
#include <hip/hip_runtime.h>
#include <hip/hip_bf16.h>

// out[i] = x_i @ Q @ x_i, x [1024,2048] fp32 binary, Q [2048,2048] fp32.
// Identity: x^T Q x == x^T Q^T x -> MFMA B-operand (N x K) = row-major Q.
// Round 6: revert to the empirically-best R2 engine (16x16x32 frags, 128x128
// block, XOR swizzle, global_load_lds). NEW: (a) NO atomics — each block
// writes a (row, n*k-slice) partial to ws, tiny reduce kernel sums 256
// partials/row (kills the 128-per-address device-scope atomic fan-in that is
// the suspected serial tail), (b) KSPLIT=16 (2048 blocks, 4-5 resident/CU),
// (c) LDS-staged x-mask epilogue (no per-lane global scalar loads).

#define B_ROWS 1024
#define N_BITS 2048

#define BM 128
#define BN 128
#define BK 64
#define KSPLIT 16
#define KPER (N_BITS / KSPLIT)   // 128
#define KITERS (KPER / BK)       // 2
#define NKB (N_BITS / BN)        // 16 n-blocks
#define NPART (NKB * KSPLIT)     // 256 partials per row

typedef __bf16 bf16_t;
typedef __bf16 bf16x8 __attribute__((ext_vector_type(8)));
typedef float f32x4 __attribute__((ext_vector_type(4)));

__device__ __forceinline__ void load16_to_lds(const void* g, void* l) {
  __builtin_amdgcn_global_load_lds(
      (__attribute__((address_space(1))) void*)(g),
      (__attribute__((address_space(3))) void*)(l),
      16, 0, 0);
}

// prep: fp32 -> bf16 for x (2M) and Q (4M) into ws.
__global__ __launch_bounds__(256) void prep_kernel(
    const float* __restrict__ x, const float* __restrict__ Q,
    bf16_t* __restrict__ xb, bf16_t* __restrict__ qb) {
  const int tid = blockIdx.x * 256 + threadIdx.x;
  const int XTH = (B_ROWS * N_BITS) / 8;  // 262144 threads cover x
  const float* src;
  bf16_t* dst;
  if (tid < XTH) {
    size_t o = (size_t)tid * 8;
    src = x + o;
    dst = xb + o;
  } else {
    size_t o = (size_t)(tid - XTH) * 8;
    src = Q + o;
    dst = qb + o;
  }
  float4 v0 = ((const float4*)src)[0];
  float4 v1 = ((const float4*)src)[1];
  union { int4 i4; __hip_bfloat16 h[8]; } u;
  u.h[0] = __float2bfloat16(v0.x);
  u.h[1] = __float2bfloat16(v0.y);
  u.h[2] = __float2bfloat16(v0.z);
  u.h[3] = __float2bfloat16(v0.w);
  u.h[4] = __float2bfloat16(v1.x);
  u.h[5] = __float2bfloat16(v1.y);
  u.h[6] = __float2bfloat16(v1.z);
  u.h[7] = __float2bfloat16(v1.w);
  ((int4*)dst)[0] = u.i4;
}

// GEMM S = Xb @ Qb^T (16x16x32 frags, R2 engine) + LDS-masked row-dot.
// 4 waves split M (each owns 32 rows x BN=128): acc = 2x8 frags.
// Writes partial[row*NPART + nkid]; NO atomics.
__global__ __launch_bounds__(256) void qubo_kernel(
    const bf16_t* __restrict__ Xb, const bf16_t* __restrict__ Qb,
    float* __restrict__ partial) {
  __shared__ bf16_t lds[(BM + BN) * BK];   // 32 KB; A at 0, B at BM*BK
  bf16_t* ldsA = lds;
  bf16_t* ldsB = lds + BM * BK;

  const int tid  = threadIdx.x;
  const int lane = tid & 63;
  const int wave = tid >> 6;     // 0..3 -> owns rows [wave*32, wave*32+32)
  const int lrow = lane & 15;
  const int quad = lane >> 4;

  const int m0    = blockIdx.y * BM;
  const int n0    = blockIdx.x * BN;
  const int kbase = blockIdx.z * KPER;
  const int nkid  = blockIdx.x * KSPLIT + blockIdx.z;  // 0..255

  // Staging (R2-verified): 32 rows x 8 chunks (16B) per pass; LDS dest linear
  // in tid (== wave_base + lane*16B as global_load_lds requires); GLOBAL chunk
  // XOR-swizzled: LDS slot s of row r holds global chunk s ^ (r&7).
  const int srow = tid >> 3;                // 0..31
  const int gch  = (tid & 7) ^ (srow & 7);  // swizzled global chunk

  f32x4 acc[2][8];
#pragma unroll
  for (int i = 0; i < 2; ++i)
#pragma unroll
    for (int j = 0; j < 8; ++j) acc[i][j] = (f32x4){0.f, 0.f, 0.f, 0.f};

  for (int kt = 0; kt < KITERS; ++kt) {
    const int k0 = kbase + kt * BK;
#pragma unroll
    for (int p = 0; p < 4; ++p) {
      const int r = p * 32 + srow;
      load16_to_lds(Xb + (size_t)(m0 + r) * N_BITS + k0 + gch * 8,
                    ldsA + r * BK + (tid & 7) * 8);
      load16_to_lds(Qb + (size_t)(n0 + r) * N_BITS + k0 + gch * 8,
                    ldsB + r * BK + (tid & 7) * 8);
    }
    __syncthreads();

    const int sw = lrow & 7;
#pragma unroll
    for (int ks = 0; ks < 2; ++ks) {
      const int ch = ((ks * 4 + quad) ^ sw) * 8;  // un-swizzled chunk offset
      bf16x8 a[2], b[8];
#pragma unroll
      for (int mi = 0; mi < 2; ++mi)
        a[mi] = *(const bf16x8*)&ldsA[(wave * 32 + mi * 16 + lrow) * BK + ch];
#pragma unroll
      for (int ni = 0; ni < 8; ++ni)
        b[ni] = *(const bf16x8*)&ldsB[(ni * 16 + lrow) * BK + ch];
#pragma unroll
      for (int mi = 0; mi < 2; ++mi)
#pragma unroll
        for (int ni = 0; ni < 8; ++ni)
          acc[mi][ni] = __builtin_amdgcn_mfma_f32_16x16x32_bf16(
              a[mi], b[ni], acc[mi][ni], 0, 0, 0);
    }
    __syncthreads();
  }

  // Stage x-mask tile X[m0:+128, n0:+128] (bf16, 32 KB) into the SAME lds:
  // 128 rows x 16 chunks = 8 per thread; dest linear per wave (R5-verified).
  bf16_t* maskL = lds;
#pragma unroll
  for (int p = 0; p < 8; ++p) {
    const int r = p * 16 + (tid >> 4);
    load16_to_lds(Xb + (size_t)(m0 + r) * N_BITS + n0 + (tid & 15) * 8,
                  maskL + r * BN + (tid & 15) * 8);
  }
  __syncthreads();

  // Epilogue. 16x16 C/D: col = lane&15, row = quad*4 + reg. Mask from LDS,
  // 16-lane shuffle reduce, one plain store per (row, nkid). No atomics.
#pragma unroll
  for (int mi = 0; mi < 2; ++mi) {
#pragma unroll
    for (int r = 0; r < 4; ++r) {
      const int rloc = wave * 32 + mi * 16 + quad * 4 + r;
      float s = 0.f;
#pragma unroll
      for (int ni = 0; ni < 8; ++ni) {
        const int cloc = ni * 16 + lrow;
        s += acc[mi][ni][r] * (float)maskL[rloc * BN + cloc];
      }
#pragma unroll
      for (int off = 1; off < 16; off <<= 1)
        s += __shfl_xor(s, off, 64);
      if (lrow == 0)
        partial[(size_t)(m0 + rloc) * NPART + nkid] = s;
    }
  }
}

// reduce: out[row] = sum over 256 partials. One block per row, fully coalesced.
__global__ __launch_bounds__(256) void reduce_kernel(
    const float* __restrict__ partial, float* __restrict__ out) {
  const int row = blockIdx.x;
  const int tid = threadIdx.x;
  float v = partial[(size_t)row * NPART + tid];
#pragma unroll
  for (int off = 1; off < 64; off <<= 1)
    v += __shfl_xor(v, off, 64);
  __shared__ float wsum[4];
  if ((tid & 63) == 0) wsum[tid >> 6] = v;
  __syncthreads();
  if (tid == 0) out[row] = wsum[0] + wsum[1] + wsum[2] + wsum[3];
}

extern "C" void kernel_launch(void* const* d_in, const int* in_sizes, int n_in,
                              void* d_out, int out_size, void* d_ws, size_t ws_size,
                              hipStream_t stream) {
  const float* x = (const float*)d_in[0];
  const float* Q = (const float*)d_in[1];
  float* out = (float*)d_out;

  bf16_t* xb = (bf16_t*)d_ws;                                        // 4 MB
  bf16_t* qb = (bf16_t*)((char*)d_ws + (size_t)B_ROWS * N_BITS * 2); // 8 MB
  float* partial = (float*)((char*)d_ws + (size_t)12 * 1024 * 1024); // 1 MB

  prep_kernel<<<3072, 256, 0, stream>>>(x, Q, xb, qb);

  dim3 grid(NKB, B_ROWS / BM, KSPLIT);  // (16, 8, 16) = 2048 blocks
  qubo_kernel<<<grid, dim3(256), 0, stream>>>(xb, qb, partial);

  reduce_kernel<<<B_ROWS, 256, 0, stream>>>(partial, out);
}